// Round 6
// baseline (327.360 us; speedup 1.0000x reference)
//
#include <hip/hip_runtime.h>
#include <math.h>

#define NLV 16
#define TBLBITS 19
#define TBLMASK ((1u << TBLBITS) - 1u)
#define P2 2654435761u
#define P3 805459861u

// dense tables for levels 0..3 (res 16,23,33,48 -> dims 17,24,34,49)
// packed with even-aligned bases (entry units): 0, 4914, 18738, 58044
#define D_BASE0 0
#define D_BASE1 4914
#define D_BASE2 18738
#define D_BASE3 58044
#define D_TOTAL 175694   // entries (float2 each)

typedef __attribute__((ext_vector_type(8))) short bf16x8;
typedef __attribute__((ext_vector_type(4))) float f32x4;

__device__ __forceinline__ unsigned f2bf(float f) {
    unsigned u = __builtin_bit_cast(unsigned, f);
    return (u + 0x7fffu + ((u >> 16) & 1u)) >> 16;   // RNE to bf16
}

// ---------------- Kernel R: repack levels 0..3 into dense arrays -----------
__global__ __launch_bounds__(256)
void dense_repack(const float* __restrict__ table, float* __restrict__ dense)
{
    const int i = blockIdx.x * 256 + threadIdx.x;
    if (i >= D_TOTAL) return;
    int g, lo, dim;
    if (i < 4913)                       { g = 0; lo = i;           dim = 17; }
    else if (i >= D_BASE1 && i < 18738) { g = 1; lo = i - D_BASE1; dim = 24; }
    else if (i >= D_BASE2 && i < 58042) { g = 2; lo = i - D_BASE2; dim = 34; }
    else if (i >= D_BASE3 && i < 175693){ g = 3; lo = i - D_BASE3; dim = 49; }
    else return;                         // padding slots
    const unsigned z = (unsigned)lo % (unsigned)dim;
    const unsigned t = (unsigned)lo / (unsigned)dim;
    const unsigned y = t % (unsigned)dim;
    const unsigned x = t / (unsigned)dim;
    const unsigned h = (x ^ y * P2 ^ z * P3) & TBLMASK;
    const float* tl = table + ((size_t)g << 20);
    const float2 v = *reinterpret_cast<const float2*>(tl + ((size_t)h << 1));
    dense[(size_t)i * 2 + 0] = v.x;
    dense[(size_t)i * 2 + 1] = v.y;
}

// ---------------- Kernel A: hash-grid encode, levels 4..15 only ------------
// grid = (npts/256, 12).  Output: encOut[(lvl-4) * npts + p] (coalesced).
__global__ __launch_bounds__(256)
void enc_kernel(const float* __restrict__ positions,
                const float* __restrict__ aabb,
                const float* __restrict__ table,
                unsigned* __restrict__ encOut, int npts,
                float r0_, float r1_, float r2_, float r3_,
                float r4_, float r5_, float r6_, float r7_,
                float r8_, float r9_, float r10_, float r11_,
                float r12_, float r13_, float r14_, float r15_)
{
    const unsigned l = blockIdx.y + 4u;          // wave-uniform level 4..15
    const unsigned p = blockIdx.x * 256u + threadIdx.x;

    const bool s0 = (l & 1u), s1 = (l & 2u), s2 = (l & 4u), s3 = (l & 8u);
    float a0 = s0 ? r1_  : r0_;
    float a1 = s0 ? r3_  : r2_;
    float a2 = s0 ? r5_  : r4_;
    float a3 = s0 ? r7_  : r6_;
    float a4 = s0 ? r9_  : r8_;
    float a5 = s0 ? r11_ : r10_;
    float a6 = s0 ? r13_ : r12_;
    float a7 = s0 ? r15_ : r14_;
    float c0 = s1 ? a1 : a0;
    float c1 = s1 ? a3 : a2;
    float c2 = s1 ? a5 : a4;
    float c3 = s1 ? a7 : a6;
    float d0 = s2 ? c1 : c0;
    float d1 = s2 ? c3 : c2;
    const float r = s3 ? d1 : d0;

    const float px = positions[p * 3 + 0];
    const float py = positions[p * 3 + 1];
    const float pz = positions[p * 3 + 2];
    const float mnx = aabb[0], mny = aabb[1], mnz = aabb[2];
    const float mxx = aabb[3], mxy = aabb[4], mxz = aabb[5];
    const float x0 = (px - mnx) / (mxx - mnx);
    const float x1 = (py - mny) / (mxy - mny);
    const float x2 = (pz - mnz) / (mxz - mnz);

    const float fx = x0 * r, fy = x1 * r, fz = x2 * r;
    const float gx = floorf(fx), gy = floorf(fy), gz = floorf(fz);
    const unsigned cx = (unsigned)gx, cy = (unsigned)gy, cz = (unsigned)gz;
    const float rx = fx - gx, ry = fy - gy, rz = fz - gz;

    const float* tl = table + ((size_t)l << 20);   // l * TBL * 2 floats
    float e0 = 0.f, e1 = 0.f;
    const bool xeven = (cx & 1u) == 0u;

    #pragma unroll
    for (int yz = 0; yz < 4; ++yz) {
        const unsigned dy = (yz >> 1) & 1, dz = yz & 1;
        const unsigned base = ((cy + dy) * P2) ^ ((cz + dz) * P3);
        const float wy = dy ? ry : 1.f - ry;
        const float wz = dz ? rz : 1.f - rz;
        const float wyz = wy * wz;
        const float wa = wyz * (1.f - rx);
        const float wb = wyz * rx;
        const unsigned i0 = (cx ^ base) & TBLMASK;

        float f0x, f0y, f1x, f1y;
        if (xeven) {
            const float4 q = *reinterpret_cast<const float4*>(
                tl + ((size_t)(i0 & ~1u) << 1));
            const bool lo = (i0 & 1u) == 0u;
            f0x = lo ? q.x : q.z;  f0y = lo ? q.y : q.w;
            f1x = lo ? q.z : q.x;  f1y = lo ? q.w : q.y;
        } else {
            const unsigned i1 = ((cx + 1u) ^ base) & TBLMASK;
            const float2 qa = *reinterpret_cast<const float2*>(tl + ((size_t)i0 << 1));
            const float2 qb = *reinterpret_cast<const float2*>(tl + ((size_t)i1 << 1));
            f0x = qa.x; f0y = qa.y; f1x = qb.x; f1y = qb.y;
        }
        e0 = fmaf(wa, f0x, e0); e0 = fmaf(wb, f1x, e0);
        e1 = fmaf(wa, f0y, e1); e1 = fmaf(wb, f1y, e1);
    }
    encOut[(size_t)(l - 4u) * npts + p] = f2bf(e0) | (f2bf(e1) << 16);
}

// ---------------- Kernel W: transpose/pad/convert weights (gridded) --------
__global__ __launch_bounds__(256)
void prep_weights(const float* __restrict__ w1, const float* __restrict__ w2,
                  const float* __restrict__ hw1, const float* __restrict__ hw2,
                  const float* __restrict__ hw3, unsigned short* __restrict__ wt)
{
    const int i = blockIdx.x * 256 + threadIdx.x;
    if (i >= 12032) return;
    float v = 0.f;
    if (i < 2560) {
        int n = i / 40, k = i % 40;
        if (k < 32) v = w1[k * 64 + n];
    } else if (i < 5120) {
        int j = i - 2560, n = j / 40, k = j % 40;
        if (k < 15) v = hw1[k * 64 + n];
    } else if (i < 6272) {
        int j = i - 5120, n = j / 72, k = j % 72;
        if (k < 64) v = w2[k * 16 + n];
    } else if (i < 10880) {
        int j = i - 6272, n = j / 72, k = j % 72;
        if (k < 64) v = hw2[k * 64 + n];
    } else {
        int j = i - 10880, n = j / 72, k = j % 72;
        if (k < 64 && n < 3) v = hw3[k * 3 + n];
    }
    wt[i] = (unsigned short)f2bf(v);
}

// dense trilinear gather for level g (0..3); returns packed bf16 pair
__device__ __forceinline__ unsigned dense_gather(
    const float* __restrict__ dt, int g, float x0, float x1, float x2)
{
    const float r  = (g & 2) ? ((g & 1) ? 48.f : 33.f) : ((g & 1) ? 23.f : 16.f);
    const int  dim = (g & 2) ? ((g & 1) ? 49 : 34) : ((g & 1) ? 24 : 17);
    const int  bse = (g & 2) ? ((g & 1) ? D_BASE3 : D_BASE2)
                             : ((g & 1) ? D_BASE1 : D_BASE0);
    const float fx = x0 * r, fy = x1 * r, fz = x2 * r;
    const float gx = floorf(fx), gy = floorf(fy), gz = floorf(fz);
    const int cx = (int)gx, cy = (int)gy, cz = (int)gz;
    const float rx = fx - gx, ry = fy - gy, rz = fz - gz;
    float e0 = 0.f, e1 = 0.f;
    #pragma unroll
    for (int xy = 0; xy < 4; ++xy) {
        const int dx = xy >> 1, dy = xy & 1;
        const int row = ((cx + dx) * dim + (cy + dy)) * dim + cz + bse;
        const float wxy = (dx ? rx : 1.f - rx) * (dy ? ry : 1.f - ry);
        const float wa = wxy * (1.f - rz), wb = wxy * rz;
        float f0x, f0y, f1x, f1y;
        if (!(row & 1)) {
            const float4 q = *reinterpret_cast<const float4*>(dt + ((size_t)row << 1));
            f0x = q.x; f0y = q.y; f1x = q.z; f1y = q.w;
        } else {
            const float2 qa = *reinterpret_cast<const float2*>(dt + ((size_t)row << 1));
            const float2 qb = *reinterpret_cast<const float2*>(dt + ((size_t)(row + 1) << 1));
            f0x = qa.x; f0y = qa.y; f1x = qb.x; f1y = qb.y;
        }
        e0 = fmaf(wa, f0x, e0); e0 = fmaf(wb, f1x, e0);
        e1 = fmaf(wa, f0y, e1); e1 = fmaf(wb, f1y, e1);
    }
    return f2bf(e0) | (f2bf(e1) << 16);
}

// ---------------- Kernel B: fused MFMA-bf16 MLP, 32 points / wave ----------
// Levels 0..3 gathered inline from dense tables (lane group g gathers level g,
// ds_bpermute redistributes); levels 4..15 read from encbuf.
__global__ __launch_bounds__(256)
void mlp_kernel(const unsigned* __restrict__ enc,        // bf16 pairs [12][npts]
                const unsigned short* __restrict__ wt,
                const float* __restrict__ dense,
                const float* __restrict__ positions,
                const float* __restrict__ aabb,
                const float* __restrict__ b1, const float* __restrict__ b2,
                const float* __restrict__ hb1, const float* __restrict__ hb2,
                const float* __restrict__ hb3,
                float* __restrict__ out, int npts)
{
    __shared__ __align__(16) unsigned short H[4][32 * 72];  // per-wave
    __shared__ float sel_lds[128];

    const int tid  = threadIdx.x;
    const int wave = tid >> 6;
    const int lane = tid & 63;
    const int col  = lane & 15;
    const int lgrp = lane >> 4;
    const int blockPt = blockIdx.x * 128;
    const int wavePt  = blockPt + wave * 32;

    const float mnx = aabb[0], mny = aabb[1], mnz = aabb[2];
    const float mxx = aabb[3], mxy = aabb[4], mxz = aabb[5];

    // ---- selector: lanes 0..31 of each wave handle its own 32 points ----
    if (lane < 32) {
        const int gp = wavePt + lane;
        const float px = positions[gp * 3 + 0];
        const float py = positions[gp * 3 + 1];
        const float pz = positions[gp * 3 + 2];
        const float x0 = (px - mnx) / (mxx - mnx);
        const float x1 = (py - mny) / (mxy - mny);
        const float x2 = (pz - mnz) / (mxz - mnz);
        const bool sel = (x0 > 0.f) && (x0 < 1.f) && (x1 > 0.f) && (x1 < 1.f) &&
                         (x2 > 0.f) && (x2 < 1.f);
        sel_lds[wave * 32 + lane] = sel ? 1.f : 0.f;
    }

    // ---- per-lane bias preloads ----
    float bias1[4], biasH1[4], biasH2[4];
    #pragma unroll
    for (int nt = 0; nt < 4; ++nt) {
        bias1[nt]  = b1[nt * 16 + col];
        biasH1[nt] = hb1[nt * 16 + col];
        biasH2[nt] = hb2[nt * 16 + col];
    }
    const float bias2 = b2[col];
    const float biasH3 = (col < 3) ? hb3[col] : 0.f;

    // ---- A-frags for layer 1: dense levels 0..3 + encbuf levels 4..15 ----
    bf16x8 a1[2];
    #pragma unroll
    for (int mt = 0; mt < 2; ++mt) {
        const int ptl = wavePt + mt * 16 + col;
        const float px = positions[ptl * 3 + 0];
        const float py = positions[ptl * 3 + 1];
        const float pz = positions[ptl * 3 + 2];
        const float x0 = (px - mnx) / (mxx - mnx);
        const float x1 = (py - mny) / (mxy - mny);
        const float x2 = (pz - mnz) / (mxz - mnz);
        // this lane gathers dense level `lgrp` for its point
        const unsigned dv = dense_gather(dense, lgrp, x0, x1, x2);
        // encbuf rows for this lane's k-slots (levels lgrp*4 .. lgrp*4+3)
        const int er = (lgrp == 0) ? 0 : (lgrp * 4 - 4);
        const unsigned e0v = enc[(size_t)(er + 0) * npts + ptl];
        const unsigned e1v = enc[(size_t)(er + 1) * npts + ptl];
        const unsigned e2v = enc[(size_t)(er + 2) * npts + ptl];
        const unsigned e3v = enc[(size_t)(er + 3) * npts + ptl];
        // redistribute dense dwords: level j of point col lives on lane col+16j
        const int cbase = col * 4;
        const unsigned d0 = (unsigned)__builtin_amdgcn_ds_bpermute(cbase,       (int)dv);
        const unsigned d1 = (unsigned)__builtin_amdgcn_ds_bpermute(cbase + 64,  (int)dv);
        const unsigned d2 = (unsigned)__builtin_amdgcn_ds_bpermute(cbase + 128, (int)dv);
        const unsigned d3 = (unsigned)__builtin_amdgcn_ds_bpermute(cbase + 192, (int)dv);
        uint4 v;
        v.x = (lgrp == 0) ? d0 : e0v;
        v.y = (lgrp == 0) ? d1 : e1v;
        v.z = (lgrp == 0) ? d2 : e2v;
        v.w = (lgrp == 0) ? d3 : e3v;
        a1[mt] = __builtin_bit_cast(bf16x8, v);
    }

    const unsigned short* w1t = wt;
    const unsigned short* w3t = wt + 2560;
    const unsigned short* w2t = wt + 5120;
    const unsigned short* w4t = wt + 6272;
    const unsigned short* w5t = wt + 10880;
    unsigned short* Hw = H[wave];

    // ================= L1: h1 = relu(enc @ w1 + b1)  [K=32, N=64] ==========
    {
        f32x4 acc[2][4];
        #pragma unroll
        for (int mt = 0; mt < 2; ++mt)
            #pragma unroll
            for (int nt = 0; nt < 4; ++nt) {
                const float b = bias1[nt];
                acc[mt][nt] = (f32x4){b, b, b, b};
            }
        #pragma unroll
        for (int nt = 0; nt < 4; ++nt) {
            const bf16x8 b = *reinterpret_cast<const bf16x8*>(
                w1t + (nt * 16 + col) * 40 + lgrp * 8);
            #pragma unroll
            for (int mt = 0; mt < 2; ++mt)
                acc[mt][nt] = __builtin_amdgcn_mfma_f32_16x16x32_bf16(
                    a1[mt], b, acc[mt][nt], 0, 0, 0);
        }
        #pragma unroll
        for (int mt = 0; mt < 2; ++mt)
            #pragma unroll
            for (int nt = 0; nt < 4; ++nt)
                #pragma unroll
                for (int rr = 0; rr < 4; ++rr) {
                    const float h = fmaxf(acc[mt][nt][rr], 0.f);
                    const int row = mt * 16 + lgrp * 4 + rr;
                    Hw[row * 72 + nt * 16 + col] = (unsigned short)f2bf(h);
                }
    }

    // ================= L2: base = h1 @ w2 + b2  [K=64, N=16] ================
    {
        f32x4 acc[2];
        #pragma unroll
        for (int mt = 0; mt < 2; ++mt)
            acc[mt] = (f32x4){bias2, bias2, bias2, bias2};
        #pragma unroll
        for (int ks = 0; ks < 2; ++ks) {
            const bf16x8 b = *reinterpret_cast<const bf16x8*>(
                w2t + col * 72 + ks * 32 + lgrp * 8);
            #pragma unroll
            for (int mt = 0; mt < 2; ++mt) {
                const bf16x8 a = *reinterpret_cast<const bf16x8*>(
                    Hw + (mt * 16 + col) * 72 + ks * 32 + lgrp * 8);
                acc[mt] = __builtin_amdgcn_mfma_f32_16x16x32_bf16(
                    a, b, acc[mt], 0, 0, 0);
            }
        }
        #pragma unroll
        for (int mt = 0; mt < 2; ++mt)
            #pragma unroll
            for (int rr = 0; rr < 4; ++rr) {
                const float base = acc[mt][rr];
                const int row = mt * 16 + lgrp * 4 + rr;
                if (col == 0) {
                    const float dn = __expf(base - 1.f) * sel_lds[wave * 32 + row];
                    out[(size_t)npts * 3 + wavePt + row] = dn;
                } else {
                    Hw[row * 72 + (col - 1)] = (unsigned short)f2bf(base);
                }
            }
        if (lane < 32) {
            const int row = lane;
            Hw[row * 72 + 15] = 0;
            const uint4 z4 = {0, 0, 0, 0};
            *reinterpret_cast<uint4*>(Hw + row * 72 + 16) = z4;
            *reinterpret_cast<uint4*>(Hw + row * 72 + 24) = z4;
        }
    }

    // ================= L3: hh1 = relu(emb @ hw1 + hb1)  [K=32(15), N=64] ====
    {
        f32x4 acc[2][4];
        #pragma unroll
        for (int mt = 0; mt < 2; ++mt)
            #pragma unroll
            for (int nt = 0; nt < 4; ++nt) {
                const float b = biasH1[nt];
                acc[mt][nt] = (f32x4){b, b, b, b};
            }
        bf16x8 a[2];
        #pragma unroll
        for (int mt = 0; mt < 2; ++mt)
            a[mt] = *reinterpret_cast<const bf16x8*>(
                Hw + (mt * 16 + col) * 72 + lgrp * 8);
        #pragma unroll
        for (int nt = 0; nt < 4; ++nt) {
            const bf16x8 b = *reinterpret_cast<const bf16x8*>(
                w3t + (nt * 16 + col) * 40 + lgrp * 8);
            #pragma unroll
            for (int mt = 0; mt < 2; ++mt)
                acc[mt][nt] = __builtin_amdgcn_mfma_f32_16x16x32_bf16(
                    a[mt], b, acc[mt][nt], 0, 0, 0);
        }
        #pragma unroll
        for (int mt = 0; mt < 2; ++mt)
            #pragma unroll
            for (int nt = 0; nt < 4; ++nt)
                #pragma unroll
                for (int rr = 0; rr < 4; ++rr) {
                    const float h = fmaxf(acc[mt][nt][rr], 0.f);
                    const int row = mt * 16 + lgrp * 4 + rr;
                    Hw[row * 72 + nt * 16 + col] = (unsigned short)f2bf(h);
                }
    }

    // ================= L4: hh2 = relu(hh1 @ hw2 + hb2)  [K=64, N=64] ========
    {
        f32x4 acc[2][4];
        #pragma unroll
        for (int mt = 0; mt < 2; ++mt)
            #pragma unroll
            for (int nt = 0; nt < 4; ++nt) {
                const float b = biasH2[nt];
                acc[mt][nt] = (f32x4){b, b, b, b};
            }
        #pragma unroll
        for (int ks = 0; ks < 2; ++ks) {
            bf16x8 a[2];
            #pragma unroll
            for (int mt = 0; mt < 2; ++mt)
                a[mt] = *reinterpret_cast<const bf16x8*>(
                    Hw + (mt * 16 + col) * 72 + ks * 32 + lgrp * 8);
            #pragma unroll
            for (int nt = 0; nt < 4; ++nt) {
                const bf16x8 b = *reinterpret_cast<const bf16x8*>(
                    w4t + (nt * 16 + col) * 72 + ks * 32 + lgrp * 8);
                #pragma unroll
                for (int mt = 0; mt < 2; ++mt)
                    acc[mt][nt] = __builtin_amdgcn_mfma_f32_16x16x32_bf16(
                        a[mt], b, acc[mt][nt], 0, 0, 0);
            }
        }
        #pragma unroll
        for (int mt = 0; mt < 2; ++mt)
            #pragma unroll
            for (int nt = 0; nt < 4; ++nt)
                #pragma unroll
                for (int rr = 0; rr < 4; ++rr) {
                    const float h = fmaxf(acc[mt][nt][rr], 0.f);
                    const int row = mt * 16 + lgrp * 4 + rr;
                    Hw[row * 72 + nt * 16 + col] = (unsigned short)f2bf(h);
                }
    }

    // ================= L5: rgb = sigmoid(hh2 @ hw3 + hb3)  [K=64, N=3] ======
    {
        f32x4 acc[2];
        #pragma unroll
        for (int mt = 0; mt < 2; ++mt)
            acc[mt] = (f32x4){biasH3, biasH3, biasH3, biasH3};
        #pragma unroll
        for (int ks = 0; ks < 2; ++ks) {
            const bf16x8 b = *reinterpret_cast<const bf16x8*>(
                w5t + col * 72 + ks * 32 + lgrp * 8);
            #pragma unroll
            for (int mt = 0; mt < 2; ++mt) {
                const bf16x8 a = *reinterpret_cast<const bf16x8*>(
                    Hw + (mt * 16 + col) * 72 + ks * 32 + lgrp * 8);
                acc[mt] = __builtin_amdgcn_mfma_f32_16x16x32_bf16(
                    a, b, acc[mt], 0, 0, 0);
            }
        }
        if (col < 3) {
            #pragma unroll
            for (int mt = 0; mt < 2; ++mt)
                #pragma unroll
                for (int rr = 0; rr < 4; ++rr) {
                    const float v = acc[mt][rr];
                    const float rgb = 1.f / (1.f + __expf(-v));
                    const int row = mt * 16 + lgrp * 4 + rr;
                    out[(size_t)(wavePt + row) * 3 + col] = rgb;
                }
        }
    }
}

extern "C" void kernel_launch(void* const* d_in, const int* in_sizes, int n_in,
                              void* d_out, int out_size, void* d_ws, size_t ws_size,
                              hipStream_t stream) {
    const float* positions = (const float*)d_in[0];
    const float* aabb      = (const float*)d_in[1];
    const float* table     = (const float*)d_in[2];
    const float* w1  = (const float*)d_in[3];
    const float* b1  = (const float*)d_in[4];
    const float* w2  = (const float*)d_in[5];
    const float* b2  = (const float*)d_in[6];
    const float* hw1 = (const float*)d_in[7];
    const float* hb1 = (const float*)d_in[8];
    const float* hw2 = (const float*)d_in[9];
    const float* hb2 = (const float*)d_in[10];
    const float* hw3 = (const float*)d_in[11];
    const float* hb3 = (const float*)d_in[12];
    float* out = (float*)d_out;

    const int npts = in_sizes[0] / 3;

    // ws layout: encbuf [12*npts dwords] | wt [12032 ushort] | dense [D_TOTAL float2]
    unsigned* encbuf = (unsigned*)d_ws;
    unsigned short* wt = (unsigned short*)((char*)d_ws + (size_t)npts * 12 * 4);
    float* dense = (float*)((char*)d_ws + (size_t)npts * 12 * 4 + 24064);

    float R[NLV];
    const double bb = exp((log(4096.0) - log(16.0)) / 15.0);
    for (int l = 0; l < NLV; ++l)
        R[l] = (float)floor(16.0 * pow(bb, (double)l));

    prep_weights<<<47, 256, 0, stream>>>(w1, w2, hw1, hw2, hw3, wt);
    dense_repack<<<(D_TOTAL + 255) / 256, 256, 0, stream>>>(table, dense);

    dim3 egrid(npts / 256, 12);
    enc_kernel<<<egrid, 256, 0, stream>>>(
        positions, aabb, table, encbuf, npts,
        R[0], R[1], R[2], R[3], R[4], R[5], R[6], R[7],
        R[8], R[9], R[10], R[11], R[12], R[13], R[14], R[15]);

    mlp_kernel<<<npts / 128, 256, 0, stream>>>(
        encbuf, wt, dense, positions, aabb, b1, b2, hb1, hb2, hb3, out, npts);
}